// Round 1
// baseline (56.829 us; speedup 1.0000x reference)
//
#include <hip/hip_runtime.h>
#include <math.h>

#define N_SPK 1024
#define M_UTT 32
#define M_ENR 16
#define M_TEST 16
#define D 512
#define N_TEST_ROWS (N_SPK * M_TEST)   // 16384

#define BM 128
#define BN 128
#define BK 64
#define LDK 72   // padded LDS leading dim (bf16 elems): 144B rows -> no 16-way conflicts

typedef __attribute__((ext_vector_type(4))) float f32x4;
typedef __attribute__((ext_vector_type(8))) short short8;
typedef __attribute__((ext_vector_type(8))) unsigned short ushort8;

__device__ __forceinline__ unsigned short f2bf(float f) {
    unsigned int u = __float_as_uint(f);
    u += 0x7FFF + ((u >> 16) & 1);   // round-to-nearest-even
    return (unsigned short)(u >> 16);
}

// ---------------------------------------------------------------------------
// Kernel 1: centroids (mean of enroll half, L2-normalize) + test-row normalize.
// Blocks [0,1024): one speaker centroid each (256 thr).
// Blocks [1024,1024+4096): 4 test rows each (1 wave per row).
// ---------------------------------------------------------------------------
__global__ __launch_bounds__(256) void prep_kernel(const float* __restrict__ emb,
                                                   unsigned short* __restrict__ cent,
                                                   unsigned short* __restrict__ test) {
    const int b = blockIdx.x;
    const int tid = threadIdx.x;
    const int lane = tid & 63;
    const int wid = tid >> 6;

    if (b < N_SPK) {
        const float* base = emb + (size_t)b * M_UTT * D;
        float a0 = 0.f, a1 = 0.f;
#pragma unroll
        for (int u = 0; u < M_ENR; ++u) {
            a0 += base[u * D + tid];
            a1 += base[u * D + tid + 256];
        }
        a0 *= (1.f / 16.f);
        a1 *= (1.f / 16.f);
        float ss = a0 * a0 + a1 * a1;
#pragma unroll
        for (int m = 1; m < 64; m <<= 1) ss += __shfl_xor(ss, m, 64);
        __shared__ float wss[4];
        if (lane == 0) wss[wid] = ss;
        __syncthreads();
        const float tot = wss[0] + wss[1] + wss[2] + wss[3];
        const float inv = 1.f / fmaxf(sqrtf(tot), 1e-8f);
        cent[b * D + tid] = f2bf(a0 * inv);
        cent[b * D + tid + 256] = f2bf(a1 * inv);
    } else {
        const int r = (b - N_SPK) * 4 + wid;   // test row 0..16383
        const int s = r >> 4, t = r & 15;
        const float* row = emb + ((size_t)s * M_UTT + M_ENR + t) * D;
        const f32x4* rv = (const f32x4*)row;
        const f32x4 v0 = rv[lane * 2];
        const f32x4 v1 = rv[lane * 2 + 1];
        float ss = v0[0]*v0[0] + v0[1]*v0[1] + v0[2]*v0[2] + v0[3]*v0[3]
                 + v1[0]*v1[0] + v1[1]*v1[1] + v1[2]*v1[2] + v1[3]*v1[3];
#pragma unroll
        for (int m = 1; m < 64; m <<= 1) ss += __shfl_xor(ss, m, 64);
        const float inv = 1.f / fmaxf(sqrtf(ss), 1e-8f);
        ushort8 o;
        o[0] = f2bf(v0[0] * inv); o[1] = f2bf(v0[1] * inv);
        o[2] = f2bf(v0[2] * inv); o[3] = f2bf(v0[3] * inv);
        o[4] = f2bf(v1[0] * inv); o[5] = f2bf(v1[1] * inv);
        o[6] = f2bf(v1[2] * inv); o[7] = f2bf(v1[3] * inv);
        *(ushort8*)&test[(size_t)r * D + lane * 8] = o;
    }
}

// ---------------------------------------------------------------------------
// Kernel 2: S = alpha * cent_n . test_n^T + beta, E = exp(S), fused row sums.
// 128x128 tile, 4 waves (2x2), 16x16x32 bf16 MFMA, BK=64, padded LDS.
// Accumulates per-row total sums and diagonal (positive) sums.
// ---------------------------------------------------------------------------
__global__ __launch_bounds__(256) void gemm_kernel(const unsigned short* __restrict__ A,  // cent 1024x512
                                                   const unsigned short* __restrict__ B,  // test 16384x512
                                                   const float* __restrict__ alpha_p,
                                                   const float* __restrict__ beta_p,
                                                   float* __restrict__ g_row,
                                                   float* __restrict__ g_pos) {
    __shared__ unsigned short As[BM * LDK];
    __shared__ unsigned short Bs[BN * LDK];
    __shared__ float rowsum[BM];
    __shared__ float possum[BM];

    const int tid = threadIdx.x;
    const int lane = tid & 63;
    const int w = tid >> 6;
    const int wr = w >> 1, wc = w & 1;
    const int bi = blockIdx.x & 7;     // 8 row-blocks  (M = 1024)
    const int bj = blockIdx.x >> 3;    // 128 col-blocks (N = 16384)
    const int row0 = bi * BM, col0 = bj * BN;

    const float alpha = *alpha_p;
    const float beta = *beta_p;

    if (tid < BM) { rowsum[tid] = 0.f; possum[tid] = 0.f; }

    f32x4 acc[4][4] = {};

    const int srow = tid >> 3;          // 0..31
    const int sc8 = (tid & 7) * 8;      // 0..56

    for (int ks = 0; ks < 8; ++ks) {
        const int k0 = ks * BK;
        ushort8 ra[4], rb[4];
#pragma unroll
        for (int it = 0; it < 4; ++it) {
            const int row = it * 32 + srow;
            ra[it] = *(const ushort8*)&A[(size_t)(row0 + row) * D + k0 + sc8];
            rb[it] = *(const ushort8*)&B[(size_t)(col0 + row) * D + k0 + sc8];
        }
        __syncthreads();   // previous tile's compute done before overwrite
#pragma unroll
        for (int it = 0; it < 4; ++it) {
            const int row = it * 32 + srow;
            *(ushort8*)&As[row * LDK + sc8] = ra[it];
            *(ushort8*)&Bs[row * LDK + sc8] = rb[it];
        }
        __syncthreads();
#pragma unroll
        for (int kk = 0; kk < BK; kk += 32) {
            short8 af[4], bf[4];
#pragma unroll
            for (int mi = 0; mi < 4; ++mi)
                af[mi] = *(const short8*)&As[(wr * 64 + mi * 16 + (lane & 15)) * LDK + kk + (lane >> 4) * 8];
#pragma unroll
            for (int ni = 0; ni < 4; ++ni)
                bf[ni] = *(const short8*)&Bs[(wc * 64 + ni * 16 + (lane & 15)) * LDK + kk + (lane >> 4) * 8];
#pragma unroll
            for (int mi = 0; mi < 4; ++mi)
#pragma unroll
                for (int ni = 0; ni < 4; ++ni)
                    acc[mi][ni] = __builtin_amdgcn_mfma_f32_16x16x32_bf16(af[mi], bf[ni], acc[mi][ni], 0, 0, 0);
        }
    }

    // Epilogue: e = exp(alpha*s + beta); per-row sums over this block's 128 cols.
    // C/D layout (16x16x32): col = lane&15, row = (lane>>4)*4 + reg   [m89]
#pragma unroll
    for (int mi = 0; mi < 4; ++mi) {
#pragma unroll
        for (int r = 0; r < 4; ++r) {
            const int lrow = wr * 64 + mi * 16 + ((lane >> 4) << 2) + r;
            const int grow = row0 + lrow;
            float tot = 0.f, pos = 0.f;
#pragma unroll
            for (int ni = 0; ni < 4; ++ni) {
                const int gcol = col0 + wc * 64 + ni * 16 + (lane & 15);
                const float e = __expf(fmaf(alpha, acc[mi][ni][r], beta));
                tot += e;
                pos += ((gcol >> 4) == grow) ? e : 0.f;
            }
#pragma unroll
            for (int m = 1; m < 16; m <<= 1) {
                tot += __shfl_xor(tot, m, 64);
                pos += __shfl_xor(pos, m, 64);
            }
            if ((lane & 15) == 0) {
                atomicAdd(&rowsum[lrow], tot);
                atomicAdd(&possum[lrow], pos);
            }
        }
    }
    __syncthreads();
    if (tid < BM) {
        atomicAdd(&g_row[row0 + tid], rowsum[tid]);
        atomicAdd(&g_pos[row0 + tid], possum[tid]);
    }
}

// ---------------------------------------------------------------------------
// Kernel 3: loss = mean(log(tot - pos) - log(pos))
// ---------------------------------------------------------------------------
__global__ __launch_bounds__(1024) void finalize_kernel(const float* __restrict__ g_row,
                                                        const float* __restrict__ g_pos,
                                                        float* __restrict__ out) {
    __shared__ float red[1024];
    const int i = threadIdx.x;
    const float pos = g_pos[i];
    const float neg = g_row[i] - pos;
    red[i] = logf(fmaxf(neg, 1e-30f)) - logf(fmaxf(pos, 1e-30f));
    __syncthreads();
    for (int s = 512; s > 0; s >>= 1) {
        if (i < s) red[i] += red[i + s];
        __syncthreads();
    }
    if (i == 0) out[0] = red[0] * (1.f / 1024.f);
}

extern "C" void kernel_launch(void* const* d_in, const int* in_sizes, int n_in,
                              void* d_out, int out_size, void* d_ws, size_t ws_size,
                              hipStream_t stream) {
    const float* emb = (const float*)d_in[0];
    // d_in[1] = labels (unused; structure is fixed by construction)
    const float* alpha_p = (const float*)d_in[2];
    const float* beta_p = (const float*)d_in[3];

    unsigned short* cent = (unsigned short*)d_ws;          // 1024*512 bf16 = 1 MB
    unsigned short* test = cent + (size_t)N_SPK * D;       // 16384*512 bf16 = 16 MB
    float* g_row = (float*)(test + (size_t)N_TEST_ROWS * D);
    float* g_pos = g_row + N_SPK;

    hipMemsetAsync(g_row, 0, 2 * N_SPK * sizeof(float), stream);

    prep_kernel<<<N_SPK + N_TEST_ROWS / 4, 256, 0, stream>>>(emb, cent, test);

    gemm_kernel<<<(N_SPK / BM) * (N_TEST_ROWS / BN), 256, 0, stream>>>(
        cent, test, alpha_p, beta_p, g_row, g_pos);

    finalize_kernel<<<1, 1024, 0, stream>>>(g_row, g_pos, (float*)d_out);
}